// Round 14
// baseline (37.896 us; speedup 1.0000x reference)
//
#include <hip/hip_runtime.h>
#include <stdint.h>

// Problem constants (match reference setup_inputs)
#define BATCH   8
#define CIMG    3
#define HFULL   512
#define WFULL   512
#define HWFULL  (HFULL * WFULL)          // 262144
#define CFEAT   64
#define HE      128
#define WE      128
#define HWE     (HE * WE)                // 16384
#define NSEG    64
#define NBSEG   (BATCH * NSEG)           // 512
#define WALL_COT 0.5f
#define MIN_FRAC 0.01f

#define NTILE_A 2048                     // A: 2048 tiles x 16 px-groups x 64ch
#define NTILE_B 2048                     // B: 2048 tiles x 1024 px
#define NBLK_STREAM (NTILE_A + NTILE_B)  // interleaved even(A)/odd(B)

// ws float layout:
// [0    .. 512)    seg counts   (atomic, zeroed)
// [512  .. 1024)   seg err sums (atomic, zeroed)
// [1024 .. 1536)   seg pos cnts (atomic, zeroed)
// [1536 .. 3584)   per-B-tile recovery numerator   (plain store, no zeroing)
// [3584 .. 5632)   per-B-tile recovery denominator (plain store, no zeroing)
// [5632 .. 136704) err[131072]: per-feature-px mean channel error (plain store)
#define WS_CNT   0
#define WS_SUM   NBSEG
#define WS_POS   (2 * NBSEG)
#define WS_BNUM  (3 * NBSEG)
#define WS_BDEN  (WS_BNUM + NTILE_B)
#define WS_ERR   (WS_BDEN + NTILE_B)
#define WS_ZERO_FLOATS (3 * NBSEG)       // only the atomic bins

typedef float vf4 __attribute__((ext_vector_type(4)));

// ---------------- Kernel 1: pure dense streams, NO scatter, NO atomics ----------
__global__ __launch_bounds__(256) void confloss_stream_kernel(
    const float* __restrict__ outputs, const float* __restrict__ inputs,
    const float* __restrict__ enc1,    const float* __restrict__ dec1,
    const float* __restrict__ masks,   float* __restrict__ ws)
{
    const int tid = threadIdx.x;
    const int idx = blockIdx.x >> 1;

    if ((blockIdx.x & 1) == 0) {
        // ---- A-tile: 16 px-groups (64 px) x all 64 channels ----
        __shared__ vf4 s_part[16][16];   // [cs][grp], 8 KB
        const int grp = tid & 15;        // px-group within tile
        const int cs  = tid >> 4;        // channel slice [0,16), 4 ch each
        const int G   = idx * 16 + grp;  // global px-group [0,32768)
        const int ba  = G >> 12;         // batch
        const int r   = (G & 4095) * 4;  // px offset in 128x128 plane
        const size_t base = ((size_t)ba * CFEAT + (size_t)cs * 4) * HWE + r;
        const float* ep = enc1 + base;
        const float* dp = dec1 + base;

        const vf4 e0 = *(const vf4*)(ep);
        const vf4 e1 = *(const vf4*)(ep + HWE);
        const vf4 e2 = *(const vf4*)(ep + 2 * HWE);
        const vf4 e3 = *(const vf4*)(ep + 3 * HWE);
        const vf4 d0 = *(const vf4*)(dp);
        const vf4 d1 = *(const vf4*)(dp + HWE);
        const vf4 d2 = *(const vf4*)(dp + 2 * HWE);
        const vf4 d3 = *(const vf4*)(dp + 3 * HWE);

        vf4 acc;
        float t0, t1, t2, t3;
        t0 = e0.x - d0.x; t1 = e1.x - d1.x; t2 = e2.x - d2.x; t3 = e3.x - d3.x;
        acc.x = t0*t0 + t1*t1 + t2*t2 + t3*t3;
        t0 = e0.y - d0.y; t1 = e1.y - d1.y; t2 = e2.y - d2.y; t3 = e3.y - d3.y;
        acc.y = t0*t0 + t1*t1 + t2*t2 + t3*t3;
        t0 = e0.z - d0.z; t1 = e1.z - d1.z; t2 = e2.z - d2.z; t3 = e3.z - d3.z;
        acc.z = t0*t0 + t1*t1 + t2*t2 + t3*t3;
        t0 = e0.w - d0.w; t1 = e1.w - d1.w; t2 = e2.w - d2.w; t3 = e3.w - d3.w;
        acc.w = t0*t0 + t1*t1 + t2*t2 + t3*t3;

        s_part[cs][grp] = acc;
        __syncthreads();

        if (tid < 16) {
            vf4 s = s_part[0][tid];
#pragma unroll
            for (int k = 1; k < 16; ++k) {
                const vf4 v = s_part[k][tid];
                s.x += v.x; s.y += v.y; s.z += v.z; s.w += v.w;
            }
            const float sc = 1.0f / (float)CFEAT;
            s.x *= sc; s.y *= sc; s.z *= sc; s.w *= sc;
            *(vf4*)(ws + WS_ERR + (size_t)(idx * 16 + tid) * 4) = s;  // coalesced 256B
        }
    } else {
        // ---- B-tile: 1024 full-res px, pure reduce, plain stores ----
        const int g = idx * 256 + tid;   // 4-px group [0, 524288)
        const int p = g * 4;
        const int b = p >> 18;           // block-uniform (1024 | 262144)
        const int r = p & (HWFULL - 1);
        const float* ob = outputs + (size_t)b * (CIMG * HWFULL) + r;
        const float* ib = inputs  + (size_t)b * (CIMG * HWFULL) + r;

        const vf4 m4 = *(const vf4*)(masks + (size_t)b * HWFULL + r);
        const vf4 o0 = *(const vf4*)(ob);
        const vf4 o1 = *(const vf4*)(ob + HWFULL);
        const vf4 o2 = *(const vf4*)(ob + 2 * HWFULL);
        const vf4 i0 = *(const vf4*)(ib);
        const vf4 i1 = *(const vf4*)(ib + HWFULL);
        const vf4 i2 = *(const vf4*)(ib + 2 * HWFULL);

        float num = 0.f, den = 0.f;
#define BPIX(mv, a0, a1, a2, b0, b1, b2)                                    \
        {                                                                   \
            float tgt, dd, mse = 0.f;                                       \
            tgt = ((mv) >= WALL_COT) ? 0.f : (b0); dd = (a0) - tgt; mse += dd*dd; \
            tgt = ((mv) >= WALL_COT) ? 0.f : (b1); dd = (a1) - tgt; mse += dd*dd; \
            tgt = ((mv) >= WALL_COT) ? 0.f : (b2); dd = (a2) - tgt; mse += dd*dd; \
            if ((mv) > 0.f) { num += mse; den += 1.f; }                     \
        }
        BPIX(m4.x, o0.x, o1.x, o2.x, i0.x, i1.x, i2.x)
        BPIX(m4.y, o0.y, o1.y, o2.y, i0.y, i1.y, i2.y)
        BPIX(m4.z, o0.z, o1.z, o2.z, i0.z, i1.z, i2.z)
        BPIX(m4.w, o0.w, o1.w, o2.w, i0.w, i1.w, i2.w)
#undef BPIX

#pragma unroll
        for (int off = 32; off >= 1; off >>= 1) {
            num += __shfl_down(num, off);
            den += __shfl_down(den, off);
        }
        __shared__ float s_rn[4], s_rd[4];
        const int w = tid >> 6;
        if ((tid & 63) == 0) { s_rn[w] = num; s_rd[w] = den; }
        __syncthreads();
        if (tid == 0) {
            ws[WS_BNUM + idx] = s_rn[0] + s_rn[1] + s_rn[2] + s_rn[3];
            ws[WS_BDEN + idx] = s_rd[0] + s_rd[1] + s_rd[2] + s_rd[3];
        }
    }
}

// ---------------- Kernel 2: histogram (tiny; all scatter+atomics live here) ----
__global__ __launch_bounds__(256) void confloss_bin_kernel(
    const float* __restrict__ masks, const int* __restrict__ segs,
    float* __restrict__ ws)
{
    const int tid = threadIdx.x;
    const int w   = tid >> 6;
    const int l   = tid & 63;
    __shared__ float hc[4][NSEG], hs[4][NSEG], hp[4][NSEG];
    hc[w][l] = 0.f; hs[w][l] = 0.f; hp[w][l] = 0.f;   // own-wave init, no barrier needed

    const int gid = blockIdx.x * 256 + tid;   // 128 blocks
    const int p   = gid * 4;                  // feature px [0,131072), 4 per thread
    const int b   = p >> 14;                  // block-uniform (1024 | 16384)
    const int r   = p & (HWE - 1);
    const int y   = r >> 7, x = r & (WE - 1);
    const int src = b * HWFULL + (y * 4) * WFULL + x * 4;

    const vf4 ev = *(const vf4*)(ws + WS_ERR + p);
    const int   s0 = segs[src],      s1 = segs[src + 4],
                s2 = segs[src + 8],  s3 = segs[src + 12];
    const float m0 = masks[src],     m1 = masks[src + 4],
                m2 = masks[src + 8], m3 = masks[src + 12];

    atomicAdd(&hs[w][s0], ev.x); atomicAdd(&hc[w][s0], 1.f);
    if (m0 > 0.f && m0 < WALL_COT) atomicAdd(&hp[w][s0], 1.f);
    atomicAdd(&hs[w][s1], ev.y); atomicAdd(&hc[w][s1], 1.f);
    if (m1 > 0.f && m1 < WALL_COT) atomicAdd(&hp[w][s1], 1.f);
    atomicAdd(&hs[w][s2], ev.z); atomicAdd(&hc[w][s2], 1.f);
    if (m2 > 0.f && m2 < WALL_COT) atomicAdd(&hp[w][s2], 1.f);
    atomicAdd(&hs[w][s3], ev.w); atomicAdd(&hc[w][s3], 1.f);
    if (m3 > 0.f && m3 < WALL_COT) atomicAdd(&hp[w][s3], 1.f);
    __syncthreads();

    if (tid < NSEG) {
        const int gb = b * NSEG + tid;   // b is block-uniform
        const float cv = hc[0][tid] + hc[1][tid] + hc[2][tid] + hc[3][tid];
        const float sv = hs[0][tid] + hs[1][tid] + hs[2][tid] + hs[3][tid];
        const float pv = hp[0][tid] + hp[1][tid] + hp[2][tid] + hp[3][tid];
        if (cv != 0.f) atomicAdd(&ws[WS_CNT + gb], cv);
        if (sv != 0.f) atomicAdd(&ws[WS_SUM + gb], sv);
        if (pv != 0.f) atomicAdd(&ws[WS_POS + gb], pv);
    }
}

// ---------------- Kernel 3: finalize ----------------
__global__ __launch_bounds__(512) void confloss_finalize_kernel(
    const float* __restrict__ ws, float* __restrict__ out)
{
    const int t = threadIdx.x;   // one per (b,seg); 4 B-partials each
    float rn = 0.f, rd = 0.f;
#pragma unroll
    for (int k = 0; k < NTILE_B / 512; ++k) {
        rn += ws[WS_BNUM + t + k * 512];
        rd += ws[WS_BDEN + t + k * 512];
    }
    const float cnt = ws[WS_CNT + t];
    const float sum = ws[WS_SUM + t];
    const float pos = ws[WS_POS + t];
    const float safe = fmaxf(cnt, 1.0f);
    const float mean = sum / safe;
    const bool valid = (cnt / (float)HWE) >= MIN_FRAC;
    const bool posf  = (pos / safe) > MIN_FRAC;
    float sel = (valid && posf) ? 1.0f : 0.0f;
    float val = mean * sel;

#pragma unroll
    for (int off = 32; off >= 1; off >>= 1) {
        val += __shfl_down(val, off);
        sel += __shfl_down(sel, off);
        rn  += __shfl_down(rn,  off);
        rd  += __shfl_down(rd,  off);
    }
    __shared__ float sv[8], ss[8], sn[8], sd[8];
    const int wid = t >> 6;
    if ((t & 63) == 0) { sv[wid] = val; ss[wid] = sel; sn[wid] = rn; sd[wid] = rd; }
    __syncthreads();
    if (t == 0) {
        float tv = 0.f, ts = 0.f, tn = 0.f, td = 0.f;
#pragma unroll
        for (int k = 0; k < 8; ++k) { tv += sv[k]; ts += ss[k]; tn += sn[k]; td += sd[k]; }
        const float flat_pos_mean = tv / fmaxf(ts, 1.0f);
        const float loss_recov = tn / fmaxf(td, 1.0f);
        out[0] = loss_recov + flat_pos_mean;
    }
}

extern "C" void kernel_launch(void* const* d_in, const int* in_sizes, int n_in,
                              void* d_out, int out_size, void* d_ws, size_t ws_size,
                              hipStream_t stream) {
    const float* outputs = (const float*)d_in[0];
    const float* inputs  = (const float*)d_in[1];
    const float* enc1    = (const float*)d_in[2];
    const float* dec1    = (const float*)d_in[3];
    const float* masks   = (const float*)d_in[4];
    const int*   segs    = (const int*)d_in[5];
    float* ws  = (float*)d_ws;
    float* out = (float*)d_out;

    // zero only the 1536-float atomic bins
    hipMemsetAsync(ws, 0, WS_ZERO_FLOATS * sizeof(float), stream);

    confloss_stream_kernel<<<NBLK_STREAM, 256, 0, stream>>>(
        outputs, inputs, enc1, dec1, masks, ws);
    confloss_bin_kernel<<<128, 256, 0, stream>>>(masks, segs, ws);
    confloss_finalize_kernel<<<1, 512, 0, stream>>>(ws, out);
}